// Round 16
// baseline (183.861 us; speedup 1.0000x reference)
//
#include <hip/hip_runtime.h>
#include <hip/hip_fp16.h>

#define N_NODES 100000
#define N_EDGES 1600000
#define NFEAT 128
#define NHID 64
#define NOUT 32

#define NPB 256                                   // nodes per bucket (dst >> 8)
#define NB ((N_NODES + NPB - 1) / NPB)            // 391 buckets
#define CAP 4608                                  // bucket window capacity
#define CCH 1024                                  // edges per scatter chunk
#define NCH ((N_EDGES + CCH - 1) / CCH)           // 1563
#define G1B ((N_NODES / 16 + 3) / 4)              // 1563 gemm1 blocks

typedef _Float16 half8 __attribute__((ext_vector_type(8)));
typedef float floatx4 __attribute__((ext_vector_type(4)));

// wave-level inclusive scan (64 lanes), then 4-wave combine: 1 barrier total.
__device__ __forceinline__ int wave_incl_scan(int v, int lane) {
#pragma unroll
    for (int d = 1; d < 64; d <<= 1) {
        int t = __shfl_up(v, d, 64);
        if (lane >= d) v += t;
    }
    return v;
}
__device__ __forceinline__ int block_excl_scan_256(int tsum, int tid, int* w4) {
    const int lane = tid & 63, wid = tid >> 6;
    int incl = wave_incl_scan(tsum, lane);
    if (lane == 63) w4[wid] = incl;
    __syncthreads();
    int wbase = 0;
    if (wid > 0) wbase += w4[0];
    if (wid > 1) wbase += w4[1];
    if (wid > 2) wbase += w4[2];
    return wbase + incl - tsum;
}

// ---------------------------------------------------------------
// prep: blocks 0-15 swizzle W1 into MFMA A-fragments; rest init gcur.
// ---------------------------------------------------------------
__global__ __launch_bounds__(64) void prep_kernel(const float* __restrict__ W1,
                                                  __half* __restrict__ wfrag,
                                                  int* __restrict__ gcur) {
    const int l = threadIdx.x;
    const int b = blockIdx.x;
    if (b < 16) {
        const int ks = b >> 2, ct = b & 3;
        const int kb = ks * 32 + (l >> 4) * 8;
        const int c  = ct * 16 + (l & 15);
        union { __half2 h2[4]; uint4 u; } pk;
#pragma unroll
        for (int j = 0; j < 4; ++j)
            pk.h2[j] = __floats2half2_rn(W1[(kb + 2 * j) * NHID + c],
                                         W1[(kb + 2 * j + 1) * NHID + c]);
        *(uint4*)&wfrag[((size_t)b * 64 + l) * 8] = pk.u;
    } else {
        int i = (b - 16) * 64 + l;
        if (i < NB) gcur[i] = i * CAP;
    }
}

// ---------------------------------------------------------------
// fused: blocks [0,NCH) = lean coarse scatter (1024-edge chunks);
// rest = MFMA gemm1. Scatter-block count now matches gemm1-block
// count -> no grid-starved tail.
// record: x = src(17b) | dstLocal(8b)<<17 ; y = val f32 bits
// ---------------------------------------------------------------
__global__ __launch_bounds__(256) void g1cs_kernel(const float* __restrict__ x,
                                                   const __half* __restrict__ wfrag,
                                                   __half* __restrict__ support,
                                                   const float* __restrict__ vals,
                                                   const int* __restrict__ src,
                                                   const int* __restrict__ dst,
                                                   int* __restrict__ gcur,
                                                   uint2* __restrict__ recsC) {
    __shared__ int cnt[NB];
    __shared__ int pos[NB];
    const int tid = threadIdx.x;

    if (blockIdx.x < NCH) {
        // ------- coarse scatter (lean, small chunks) -------
        const int cbase0 = blockIdx.x * CCH;
        for (int i = tid; i < NB; i += 256) cnt[i] = 0;
        int dstv[CCH / 256];
        __syncthreads();
#pragma unroll
        for (int k = 0; k < CCH / 256; ++k) {
            int e = cbase0 + k * 256 + tid;
            int d = (e < N_EDGES) ? dst[e] : -1;
            dstv[k] = d;
            if (d >= 0) atomicAdd(&cnt[d >> 8], 1);
        }
        __syncthreads();
        for (int b = tid; b < NB; b += 256) {
            int c = cnt[b];
            pos[b] = c ? atomicAdd(&gcur[b], c) : 0;
        }
        __syncthreads();
#pragma unroll
        for (int k = 0; k < CCH / 256; ++k) {
            int e = cbase0 + k * 256 + tid;
            int d = dstv[k];
            if (d >= 0) {
                int b = d >> 8;
                int slot = atomicAdd(&pos[b], 1);
                if (slot < (b + 1) * CAP)
                    recsC[slot] = make_uint2((unsigned)src[e] |
                                             ((unsigned)(d & (NPB - 1)) << 17),
                                             __float_as_uint(vals[e]));
            }
        }
    } else {
        // ------- MFMA gemm1: support = x @ W1 -------
        const int lane = tid & 63;
        const int tile = (blockIdx.x - NCH) * 4 + (tid >> 6);
        const int n0 = tile * 16;
        if (n0 >= N_NODES) return;

        half8 a[4][4];
#pragma unroll
        for (int ks = 0; ks < 4; ++ks)
#pragma unroll
            for (int ct = 0; ct < 4; ++ct)
                a[ks][ct] = *(const half8*)&wfrag[((size_t)(ks * 4 + ct) * 64 + lane) * 8];

        floatx4 acc[4];
#pragma unroll
        for (int ct = 0; ct < 4; ++ct) acc[ct] = (floatx4){0.f, 0.f, 0.f, 0.f};

        const int node = n0 + (lane & 15);
        const float* xrow = x + (size_t)node * NFEAT + (lane >> 4) * 8;

#pragma unroll
        for (int ks = 0; ks < 4; ++ks) {
            float4 f0 = *(const float4*)(xrow + ks * 32);
            float4 f1 = *(const float4*)(xrow + ks * 32 + 4);
            union { __half2 h2[4]; half8 v; } bv;
            bv.h2[0] = __floats2half2_rn(f0.x, f0.y);
            bv.h2[1] = __floats2half2_rn(f0.z, f0.w);
            bv.h2[2] = __floats2half2_rn(f1.x, f1.y);
            bv.h2[3] = __floats2half2_rn(f1.z, f1.w);
#pragma unroll
            for (int ct = 0; ct < 4; ++ct)
                acc[ct] = __builtin_amdgcn_mfma_f32_16x16x32_f16(a[ks][ct], bv.v, acc[ct], 0, 0, 0);
        }

        __half* srow = support + (size_t)node * NHID + (lane >> 4) * 4;
#pragma unroll
        for (int ct = 0; ct < 4; ++ct) {
            union { __half2 h2[2]; uint2 u; } pk;
            pk.h2[0] = __floats2half2_rn(acc[ct][0], acc[ct][1]);
            pk.h2[1] = __floats2half2_rn(acc[ct][2], acc[ct][3]);
            *(uint2*)&srow[ct * 16] = pk.u;
        }
    }
}

// ---------------------------------------------------------------
// fine sort: counting-sort each bucket window into exact node order
// ---------------------------------------------------------------
__global__ __launch_bounds__(256) void fine_sort_kernel(const int* __restrict__ gcur,
                                                        const uint2* __restrict__ recsC,
                                                        uint2* __restrict__ recs2,
                                                        int* __restrict__ offs,
                                                        int* __restrict__ ends) {
    __shared__ int cnt[NPB];
    __shared__ int cur[NPB];
    __shared__ int w4[4];
    const int tid = threadIdx.x;
    const int b = blockIdx.x;
    const int s = b * CAP;
    const int e = min(gcur[b], s + CAP);
    cnt[tid] = 0;
    __syncthreads();
    for (int i = s + tid; i < e; i += 256)
        atomicAdd(&cnt[(recsC[i].x >> 17) & (NPB - 1)], 1);
    __syncthreads();
    int v = cnt[tid];
    int excl = block_excl_scan_256(v, tid, w4);
    cur[tid] = excl;
    const int node = b * NPB + tid;
    if (node < N_NODES) {
        offs[node] = s + excl;
        ends[node] = s + excl + v;
    }
    __syncthreads();
    for (int i = s + tid; i < e; i += 256) {
        uint2 r = recsC[i];
        int dl = (r.x >> 17) & (NPB - 1);
        int p = atomicAdd(&cur[dl], 1);
        recs2[s + p] = make_uint2(r.x & 0x1FFFF, r.y);
    }
}

// ---------------------------------------------------------------
// SpMM1: h[d,:64] (fp16) = relu( sum val*support[src,:] + b1 )
// wave per node; 8 lanes/edge; direct record loads; LDS
// transpose-reduce epilogue; coalesced 2B/lane store.
// ---------------------------------------------------------------
__global__ __launch_bounds__(256) void spmm1_kernel(const int* __restrict__ offs,
                                                    const int* __restrict__ ends,
                                                    const uint2* __restrict__ recs,
                                                    const __half* __restrict__ dense,
                                                    const float* __restrict__ b1,
                                                    __half* __restrict__ h) {
    __shared__ float red[4][8][65];
    const int tid = threadIdx.x;
    const int lane = tid & 63;
    const int wid = tid >> 6;
    const int d = blockIdx.x * 4 + wid;
    if (d >= N_NODES) return;
    const int g = lane >> 3, q = lane & 7;
    float acc[8];
#pragma unroll
    for (int j = 0; j < 8; ++j) acc[j] = 0.f;

    const int start = offs[d], end = ends[d];
    for (int e = start + g; e < end; e += 8) {
        uint2 r = recs[e];
        float v = __uint_as_float(r.y);
        union { uint4 u; __half2 h2[4]; } rw;
        rw.u = *(const uint4*)((const char*)dense + ((size_t)r.x << 7) + (q << 4));
#pragma unroll
        for (int j = 0; j < 4; ++j) {
            float2 f = __half22float2(rw.h2[j]);
            acc[2 * j]     += v * f.x;
            acc[2 * j + 1] += v * f.y;
        }
    }
#pragma unroll
    for (int j = 0; j < 8; ++j) red[wid][g][q * 8 + j] = acc[j];
    __builtin_amdgcn_wave_barrier();
    float s = 0.f;
#pragma unroll
    for (int gg = 0; gg < 8; ++gg) s += red[wid][gg][lane];
    float hv = fmaxf(s + b1[lane], 0.f);
    h[(size_t)d * NHID + lane] = __float2half(hv);
}

// ---------------------------------------------------------------
// GEMM2: s2[N,32] (fp16) = h[N,64] (fp16) @ W2[64,32]
// ---------------------------------------------------------------
__global__ __launch_bounds__(256) void gemm2_kernel(const __half* __restrict__ h,
                                                    const float* __restrict__ W2,
                                                    __half* __restrict__ s2) {
    __shared__ float wlds[NHID * NOUT];        // 8 KB
    const int tid = threadIdx.x;
    for (int i = tid; i < NHID * NOUT; i += 256) wlds[i] = W2[i];

    const int cg = (tid & 7) * 4;
    const int ng = tid >> 3;
    const int n0 = blockIdx.x * 128 + ng * 4;

    int nidx[4];
#pragma unroll
    for (int i = 0; i < 4; ++i) {
        int n = n0 + i;
        nidx[i] = (n < N_NODES) ? n : (N_NODES - 1);
    }
    __syncthreads();

    float acc[4][4];
#pragma unroll
    for (int i = 0; i < 4; ++i)
#pragma unroll
        for (int j = 0; j < 4; ++j) acc[i][j] = 0.f;

    for (int k0 = 0; k0 < NHID; k0 += 8) {
        float hx[4][8];
#pragma unroll
        for (int i = 0; i < 4; ++i) {
            union { float4 f4; __half2 h2[4]; } u;
            u.f4 = *(const float4*)&h[(size_t)nidx[i] * NHID + k0];
#pragma unroll
            for (int j = 0; j < 4; ++j) {
                float2 f = __half22float2(u.h2[j]);
                hx[i][j * 2]     = f.x;
                hx[i][j * 2 + 1] = f.y;
            }
        }
#pragma unroll
        for (int kk = 0; kk < 8; ++kk) {
            float4 w = *(const float4*)&wlds[(k0 + kk) * NOUT + cg];
#pragma unroll
            for (int i = 0; i < 4; ++i) {
                float xv = hx[i][kk];
                acc[i][0] += w.x * xv; acc[i][1] += w.y * xv;
                acc[i][2] += w.z * xv; acc[i][3] += w.w * xv;
            }
        }
    }
#pragma unroll
    for (int i = 0; i < 4; ++i) {
        int n = n0 + i;
        if (n < N_NODES) {
            union { __half2 h2[2]; uint2 u; } pk;
            pk.h2[0] = __floats2half2_rn(acc[i][0], acc[i][1]);
            pk.h2[1] = __floats2half2_rn(acc[i][2], acc[i][3]);
            *(uint2*)&s2[(size_t)n * NOUT + cg] = pk.u;
        }
    }
}

// ---------------------------------------------------------------
// SpMM2: out[d,:32] (fp32) = sum val*s2[src,:] + b2
// ---------------------------------------------------------------
__global__ __launch_bounds__(256) void spmm2_kernel(const int* __restrict__ offs,
                                                    const int* __restrict__ ends,
                                                    const uint2* __restrict__ recs,
                                                    const __half* __restrict__ dense,
                                                    const float* __restrict__ b2,
                                                    float* __restrict__ out) {
    __shared__ float red[4][16][33];
    const int tid = threadIdx.x;
    const int lane = tid & 63;
    const int wid = tid >> 6;
    const int d = blockIdx.x * 4 + wid;
    if (d >= N_NODES) return;
    const int g = lane >> 2, q = lane & 3;
    float acc[8];
#pragma unroll
    for (int j = 0; j < 8; ++j) acc[j] = 0.f;

    const int start = offs[d], end = ends[d];
    for (int e = start + g; e < end; e += 16) {
        uint2 r = recs[e];
        float v = __uint_as_float(r.y);
        union { uint4 u; __half2 h2[4]; } rw;
        rw.u = *(const uint4*)((const char*)dense + ((size_t)r.x << 6) + (q << 4));
#pragma unroll
        for (int j = 0; j < 4; ++j) {
            float2 f = __half22float2(rw.h2[j]);
            acc[2 * j]     += v * f.x;
            acc[2 * j + 1] += v * f.y;
        }
    }
#pragma unroll
    for (int j = 0; j < 8; ++j) red[wid][g][q * 8 + j] = acc[j];
    __builtin_amdgcn_wave_barrier();
    const int f = lane & 31, hi = lane >> 5;
    float s = 0.f;
#pragma unroll
    for (int t = 0; t < 8; ++t) s += red[wid][hi * 8 + t][f];
    s += __shfl_xor(s, 32, 64);
    if (hi == 0) out[(size_t)d * NOUT + f] = s + b2[f];
}

extern "C" void kernel_launch(void* const* d_in, const int* in_sizes, int n_in,
                              void* d_out, int out_size, void* d_ws, size_t ws_size,
                              hipStream_t stream) {
    const float* x        = (const float*)d_in[0];
    const float* adj_vals = (const float*)d_in[1];
    const float* W1       = (const float*)d_in[2];
    const float* b1       = (const float*)d_in[3];
    const float* W2       = (const float*)d_in[4];
    const float* b2       = (const float*)d_in[5];
    const int*   esrc     = (const int*)d_in[6];
    const int*   edst     = (const int*)d_in[7];
    float*       out      = (float*)d_out;

    // ws layout (~55.3 MB, all regions rewritten every call):
    //   support[12.8MB] (s2 aliases; support dead after spmm1) | h[12.8MB]
    //   recsC[14.41MB] | recs2[14.41MB] | offs | ends | gcur | wfrag
    char* W = (char*)d_ws;
    __half* support = (__half*)W;
    __half* h       = (__half*)(W + 12800000);
    uint2*  recsC   = (uint2*)(W + 25600000);
    uint2*  recs2   = (uint2*)(W + 25600000 + (size_t)NB * CAP * 8);
    int*    IW      = (int*)(W + 25600000 + 2 * (size_t)NB * CAP * 8);
    int*    offs    = IW;                      // N
    int*    ends    = IW + 100032;             // N
    int*    gcur    = IW + 200064;             // NB
    __half* wfrag   = (__half*)(IW + 200064 + 512);  // 16 KB
    __half* s2      = support;

    // 1. prep: wfrag swizzle + gcur init
    prep_kernel<<<16 + (NB + 63) / 64, 64, 0, stream>>>(W1, wfrag, gcur);

    // 2. fused: lean coarse scatter (small chunks) | MFMA gemm1
    g1cs_kernel<<<NCH + G1B, 256, 0, stream>>>(x, wfrag, support,
                                               adj_vals, esrc, edst, gcur, recsC);

    // 3. fine sort -> recs2, offs/ends
    fine_sort_kernel<<<NB, 256, 0, stream>>>(gcur, recsC, recs2, offs, ends);

    // 4. h = relu(A @ support + b1)
    spmm1_kernel<<<(N_NODES + 3) / 4, 256, 0, stream>>>(offs, ends, recs2,
                                                        support, b1, h);

    // 5. s2 = h @ W2   (into support region)
    gemm2_kernel<<<(N_NODES + 127) / 128, 256, 0, stream>>>(h, W2, s2);

    // 6. out = A @ s2 + b2
    spmm2_kernel<<<(N_NODES + 3) / 4, 256, 0, stream>>>(offs, ends, recs2,
                                                        s2, b2, out);
}

// Round 17
// 151.376 us; speedup vs baseline: 1.2146x; 1.2146x over previous
//
#include <hip/hip_runtime.h>
#include <hip/hip_fp16.h>

#define N_NODES 100000
#define N_EDGES 1600000
#define NFEAT 128
#define NHID 64
#define NOUT 32

#define NPB 256                                   // nodes per bucket (dst >> 8)
#define NB ((N_NODES + NPB - 1) / NPB)            // 391 buckets
#define CAP 4608                                  // bucket window capacity
#define CCH 2048                                  // edges per scatter chunk
#define NCH ((N_EDGES + CCH - 1) / CCH)           // 782
#define G1B ((N_NODES / 16 + 3) / 4)              // 1563 gemm1 blocks

typedef _Float16 half8 __attribute__((ext_vector_type(8)));
typedef float floatx4 __attribute__((ext_vector_type(4)));

// wave-level inclusive scan (64 lanes), then 4-wave combine: 1 barrier total.
__device__ __forceinline__ int wave_incl_scan(int v, int lane) {
#pragma unroll
    for (int d = 1; d < 64; d <<= 1) {
        int t = __shfl_up(v, d, 64);
        if (lane >= d) v += t;
    }
    return v;
}
__device__ __forceinline__ int block_excl_scan_256(int tsum, int tid, int* w4) {
    const int lane = tid & 63, wid = tid >> 6;
    int incl = wave_incl_scan(tsum, lane);
    if (lane == 63) w4[wid] = incl;
    __syncthreads();
    int wbase = 0;
    if (wid > 0) wbase += w4[0];
    if (wid > 1) wbase += w4[1];
    if (wid > 2) wbase += w4[2];
    return wbase + incl - tsum;
}

// ---------------------------------------------------------------
// prep: blocks 0-15 swizzle W1 into MFMA A-fragments; rest init gcur.
// ---------------------------------------------------------------
__global__ __launch_bounds__(64) void prep_kernel(const float* __restrict__ W1,
                                                  __half* __restrict__ wfrag,
                                                  int* __restrict__ gcur) {
    const int l = threadIdx.x;
    const int b = blockIdx.x;
    if (b < 16) {
        const int ks = b >> 2, ct = b & 3;
        const int kb = ks * 32 + (l >> 4) * 8;
        const int c  = ct * 16 + (l & 15);
        union { __half2 h2[4]; uint4 u; } pk;
#pragma unroll
        for (int j = 0; j < 4; ++j)
            pk.h2[j] = __floats2half2_rn(W1[(kb + 2 * j) * NHID + c],
                                         W1[(kb + 2 * j + 1) * NHID + c]);
        *(uint4*)&wfrag[((size_t)b * 64 + l) * 8] = pk.u;
    } else {
        int i = (b - 16) * 64 + l;
        if (i < NB) gcur[i] = i * CAP;
    }
}

// ---------------------------------------------------------------
// coarse scatter (standalone, R14-proven shape): LDS regroup ->
// 1 reservation atomic per bucket -> coalesced run writeout.
// CCH=2048 -> runs of ~5.2 records; WRITE ~32MB (best measured).
// record: x = src(17b) | dstLocal(8b)<<17 ; y = val f32 bits
// ---------------------------------------------------------------
__global__ __launch_bounds__(256) void coarse_scatter_kernel(const float* __restrict__ vals,
                                                             const int* __restrict__ src,
                                                             const int* __restrict__ dst,
                                                             int* __restrict__ gcur,
                                                             uint2* __restrict__ recsC) {
    __shared__ int cnt[NB];
    __shared__ int sbase[NB];
    __shared__ int cur[NB];
    __shared__ int gbase[NB];
    __shared__ uint2 rl[CCH];                   // 16 KB
    __shared__ unsigned short slotB[CCH];       // 4 KB
    __shared__ int w4[4];
    const int tid = threadIdx.x;
    const int cbase0 = blockIdx.x * CCH;
    const int m = min(CCH, N_EDGES - cbase0);

    for (int i = tid; i < NB; i += 256) cnt[i] = 0;
    int dstv[CCH / 256];
    __syncthreads();
#pragma unroll
    for (int k = 0; k < CCH / 256; ++k) {
        int e = cbase0 + k * 256 + tid;
        int d = (e < N_EDGES) ? dst[e] : -1;
        dstv[k] = d;
        if (d >= 0) atomicAdd(&cnt[d >> 8], 1);
    }
    __syncthreads();
    {   // exclusive scan cnt -> sbase, init cur (wave scan, 1 barrier)
        int v[4]; int tsum = 0;
#pragma unroll
        for (int i = 0; i < 4; ++i) {
            int idx = tid * 4 + i;
            v[i] = (idx < NB) ? cnt[idx] : 0;
            tsum += v[i];
        }
        int excl = block_excl_scan_256(tsum, tid, w4);
#pragma unroll
        for (int i = 0; i < 4; ++i) {
            int idx = tid * 4 + i;
            if (idx < NB) { sbase[idx] = excl; cur[idx] = excl; excl += v[i]; }
        }
    }
    __syncthreads();
    for (int b = tid; b < NB; b += 256) {
        int c = cnt[b];
        gbase[b] = c ? atomicAdd(&gcur[b], c) : 0;
    }
#pragma unroll
    for (int k = 0; k < CCH / 256; ++k) {
        int e = cbase0 + k * 256 + tid;
        int d = dstv[k];
        if (d >= 0) {
            int b = d >> 8;
            int slot = atomicAdd(&cur[b], 1);
            rl[slot] = make_uint2((unsigned)src[e] | ((unsigned)(d & (NPB - 1)) << 17),
                                  __float_as_uint(vals[e]));
            slotB[slot] = (unsigned short)b;
        }
    }
    __syncthreads();
    for (int i = tid; i < m; i += 256) {
        int b = slotB[i];
        int idx = gbase[b] + (i - sbase[b]);
        if (idx < (b + 1) * CAP) recsC[idx] = rl[i];
    }
}

// ---------------------------------------------------------------
// fused: blocks [0,NB) = fine sort (long pole, dispatched first);
// blocks [NB, NB+G1B) = MFMA gemm1 backfill. fine_sort is
// L2/LDS-bound with 391 blocks; gemm1's 1563 VMEM/MFMA blocks
// fill the idle CUs. LDS only ~2.1KB.
// ---------------------------------------------------------------
__global__ __launch_bounds__(256) void fsg1_kernel(const int* __restrict__ gcur,
                                                   const uint2* __restrict__ recsC,
                                                   uint2* __restrict__ recs2,
                                                   int* __restrict__ offs,
                                                   int* __restrict__ ends,
                                                   const float* __restrict__ x,
                                                   const __half* __restrict__ wfrag,
                                                   __half* __restrict__ support) {
    __shared__ int cnt[NPB];
    __shared__ int cur[NPB];
    __shared__ int w4[4];
    const int tid = threadIdx.x;

    if (blockIdx.x < NB) {
        // ------- fine sort: counting-sort bucket window into node order -------
        const int b = blockIdx.x;
        const int s = b * CAP;
        const int e = min(gcur[b], s + CAP);
        cnt[tid] = 0;
        __syncthreads();
        for (int i = s + tid; i < e; i += 256)
            atomicAdd(&cnt[(recsC[i].x >> 17) & (NPB - 1)], 1);
        __syncthreads();
        int v = cnt[tid];
        int excl = block_excl_scan_256(v, tid, w4);
        cur[tid] = excl;
        const int node = b * NPB + tid;
        if (node < N_NODES) {
            offs[node] = s + excl;
            ends[node] = s + excl + v;
        }
        __syncthreads();
        for (int i = s + tid; i < e; i += 256) {
            uint2 r = recsC[i];
            int dl = (r.x >> 17) & (NPB - 1);
            int p = atomicAdd(&cur[dl], 1);
            recs2[s + p] = make_uint2(r.x & 0x1FFFF, r.y);
        }
    } else {
        // ------- MFMA gemm1: support = x @ W1 -------
        const int lane = tid & 63;
        const int tile = (blockIdx.x - NB) * 4 + (tid >> 6);
        const int n0 = tile * 16;
        if (n0 >= N_NODES) return;

        half8 a[4][4];
#pragma unroll
        for (int ks = 0; ks < 4; ++ks)
#pragma unroll
            for (int ct = 0; ct < 4; ++ct)
                a[ks][ct] = *(const half8*)&wfrag[((size_t)(ks * 4 + ct) * 64 + lane) * 8];

        floatx4 acc[4];
#pragma unroll
        for (int ct = 0; ct < 4; ++ct) acc[ct] = (floatx4){0.f, 0.f, 0.f, 0.f};

        const int node = n0 + (lane & 15);
        const float* xrow = x + (size_t)node * NFEAT + (lane >> 4) * 8;

#pragma unroll
        for (int ks = 0; ks < 4; ++ks) {
            float4 f0 = *(const float4*)(xrow + ks * 32);
            float4 f1 = *(const float4*)(xrow + ks * 32 + 4);
            union { __half2 h2[4]; half8 v; } bv;
            bv.h2[0] = __floats2half2_rn(f0.x, f0.y);
            bv.h2[1] = __floats2half2_rn(f0.z, f0.w);
            bv.h2[2] = __floats2half2_rn(f1.x, f1.y);
            bv.h2[3] = __floats2half2_rn(f1.z, f1.w);
#pragma unroll
            for (int ct = 0; ct < 4; ++ct)
                acc[ct] = __builtin_amdgcn_mfma_f32_16x16x32_f16(a[ks][ct], bv.v, acc[ct], 0, 0, 0);
        }

        __half* srow = support + (size_t)node * NHID + (lane >> 4) * 4;
#pragma unroll
        for (int ct = 0; ct < 4; ++ct) {
            union { __half2 h2[2]; uint2 u; } pk;
            pk.h2[0] = __floats2half2_rn(acc[ct][0], acc[ct][1]);
            pk.h2[1] = __floats2half2_rn(acc[ct][2], acc[ct][3]);
            *(uint2*)&srow[ct * 16] = pk.u;
        }
    }
}

// ---------------------------------------------------------------
// SpMM1: h[d,:64] (fp16) = relu( sum val*support[src,:] + b1 )
// wave per node; 8 lanes/edge; direct record loads; LDS
// transpose-reduce epilogue; coalesced 2B/lane store.
// ---------------------------------------------------------------
__global__ __launch_bounds__(256) void spmm1_kernel(const int* __restrict__ offs,
                                                    const int* __restrict__ ends,
                                                    const uint2* __restrict__ recs,
                                                    const __half* __restrict__ dense,
                                                    const float* __restrict__ b1,
                                                    __half* __restrict__ h) {
    __shared__ float red[4][8][65];
    const int tid = threadIdx.x;
    const int lane = tid & 63;
    const int wid = tid >> 6;
    const int d = blockIdx.x * 4 + wid;
    if (d >= N_NODES) return;
    const int g = lane >> 3, q = lane & 7;
    float acc[8];
#pragma unroll
    for (int j = 0; j < 8; ++j) acc[j] = 0.f;

    const int start = offs[d], end = ends[d];
    for (int e = start + g; e < end; e += 8) {
        uint2 r = recs[e];
        float v = __uint_as_float(r.y);
        union { uint4 u; __half2 h2[4]; } rw;
        rw.u = *(const uint4*)((const char*)dense + ((size_t)r.x << 7) + (q << 4));
#pragma unroll
        for (int j = 0; j < 4; ++j) {
            float2 f = __half22float2(rw.h2[j]);
            acc[2 * j]     += v * f.x;
            acc[2 * j + 1] += v * f.y;
        }
    }
#pragma unroll
    for (int j = 0; j < 8; ++j) red[wid][g][q * 8 + j] = acc[j];
    __builtin_amdgcn_wave_barrier();
    float s = 0.f;
#pragma unroll
    for (int gg = 0; gg < 8; ++gg) s += red[wid][gg][lane];
    float hv = fmaxf(s + b1[lane], 0.f);
    h[(size_t)d * NHID + lane] = __float2half(hv);
}

// ---------------------------------------------------------------
// GEMM2: s2[N,32] (fp16) = h[N,64] (fp16) @ W2[64,32]
// ---------------------------------------------------------------
__global__ __launch_bounds__(256) void gemm2_kernel(const __half* __restrict__ h,
                                                    const float* __restrict__ W2,
                                                    __half* __restrict__ s2) {
    __shared__ float wlds[NHID * NOUT];        // 8 KB
    const int tid = threadIdx.x;
    for (int i = tid; i < NHID * NOUT; i += 256) wlds[i] = W2[i];

    const int cg = (tid & 7) * 4;
    const int ng = tid >> 3;
    const int n0 = blockIdx.x * 128 + ng * 4;

    int nidx[4];
#pragma unroll
    for (int i = 0; i < 4; ++i) {
        int n = n0 + i;
        nidx[i] = (n < N_NODES) ? n : (N_NODES - 1);
    }
    __syncthreads();

    float acc[4][4];
#pragma unroll
    for (int i = 0; i < 4; ++i)
#pragma unroll
        for (int j = 0; j < 4; ++j) acc[i][j] = 0.f;

    for (int k0 = 0; k0 < NHID; k0 += 8) {
        float hx[4][8];
#pragma unroll
        for (int i = 0; i < 4; ++i) {
            union { float4 f4; __half2 h2[4]; } u;
            u.f4 = *(const float4*)&h[(size_t)nidx[i] * NHID + k0];
#pragma unroll
            for (int j = 0; j < 4; ++j) {
                float2 f = __half22float2(u.h2[j]);
                hx[i][j * 2]     = f.x;
                hx[i][j * 2 + 1] = f.y;
            }
        }
#pragma unroll
        for (int kk = 0; kk < 8; ++kk) {
            float4 w = *(const float4*)&wlds[(k0 + kk) * NOUT + cg];
#pragma unroll
            for (int i = 0; i < 4; ++i) {
                float xv = hx[i][kk];
                acc[i][0] += w.x * xv; acc[i][1] += w.y * xv;
                acc[i][2] += w.z * xv; acc[i][3] += w.w * xv;
            }
        }
    }
#pragma unroll
    for (int i = 0; i < 4; ++i) {
        int n = n0 + i;
        if (n < N_NODES) {
            union { __half2 h2[2]; uint2 u; } pk;
            pk.h2[0] = __floats2half2_rn(acc[i][0], acc[i][1]);
            pk.h2[1] = __floats2half2_rn(acc[i][2], acc[i][3]);
            *(uint2*)&s2[(size_t)n * NOUT + cg] = pk.u;
        }
    }
}

// ---------------------------------------------------------------
// SpMM2: out[d,:32] (fp32) = sum val*s2[src,:] + b2
// ---------------------------------------------------------------
__global__ __launch_bounds__(256) void spmm2_kernel(const int* __restrict__ offs,
                                                    const int* __restrict__ ends,
                                                    const uint2* __restrict__ recs,
                                                    const __half* __restrict__ dense,
                                                    const float* __restrict__ b2,
                                                    float* __restrict__ out) {
    __shared__ float red[4][16][33];
    const int tid = threadIdx.x;
    const int lane = tid & 63;
    const int wid = tid >> 6;
    const int d = blockIdx.x * 4 + wid;
    if (d >= N_NODES) return;
    const int g = lane >> 2, q = lane & 3;
    float acc[8];
#pragma unroll
    for (int j = 0; j < 8; ++j) acc[j] = 0.f;

    const int start = offs[d], end = ends[d];
    for (int e = start + g; e < end; e += 16) {
        uint2 r = recs[e];
        float v = __uint_as_float(r.y);
        union { uint4 u; __half2 h2[4]; } rw;
        rw.u = *(const uint4*)((const char*)dense + ((size_t)r.x << 6) + (q << 4));
#pragma unroll
        for (int j = 0; j < 4; ++j) {
            float2 f = __half22float2(rw.h2[j]);
            acc[2 * j]     += v * f.x;
            acc[2 * j + 1] += v * f.y;
        }
    }
#pragma unroll
    for (int j = 0; j < 8; ++j) red[wid][g][q * 8 + j] = acc[j];
    __builtin_amdgcn_wave_barrier();
    const int f = lane & 31, hi = lane >> 5;
    float s = 0.f;
#pragma unroll
    for (int t = 0; t < 8; ++t) s += red[wid][hi * 8 + t][f];
    s += __shfl_xor(s, 32, 64);
    if (hi == 0) out[(size_t)d * NOUT + f] = s + b2[f];
}

extern "C" void kernel_launch(void* const* d_in, const int* in_sizes, int n_in,
                              void* d_out, int out_size, void* d_ws, size_t ws_size,
                              hipStream_t stream) {
    const float* x        = (const float*)d_in[0];
    const float* adj_vals = (const float*)d_in[1];
    const float* W1       = (const float*)d_in[2];
    const float* b1       = (const float*)d_in[3];
    const float* W2       = (const float*)d_in[4];
    const float* b2       = (const float*)d_in[5];
    const int*   esrc     = (const int*)d_in[6];
    const int*   edst     = (const int*)d_in[7];
    float*       out      = (float*)d_out;

    // ws layout (~55.3 MB, all regions rewritten every call):
    //   support[12.8MB] (s2 aliases; support dead after spmm1) | h[12.8MB]
    //   recsC[14.41MB] | recs2[14.41MB] | offs | ends | gcur | wfrag
    char* W = (char*)d_ws;
    __half* support = (__half*)W;
    __half* h       = (__half*)(W + 12800000);
    uint2*  recsC   = (uint2*)(W + 25600000);
    uint2*  recs2   = (uint2*)(W + 25600000 + (size_t)NB * CAP * 8);
    int*    IW      = (int*)(W + 25600000 + 2 * (size_t)NB * CAP * 8);
    int*    offs    = IW;                      // N
    int*    ends    = IW + 100032;             // N
    int*    gcur    = IW + 200064;             // NB
    __half* wfrag   = (__half*)(IW + 200064 + 512);  // 16 KB
    __half* s2      = support;

    // 1. prep: wfrag swizzle + gcur init
    prep_kernel<<<16 + (NB + 63) / 64, 64, 0, stream>>>(W1, wfrag, gcur);

    // 2. coarse scatter (standalone, regroup writeout)
    coarse_scatter_kernel<<<NCH, 256, 0, stream>>>(adj_vals, esrc, edst, gcur, recsC);

    // 3. fused: fine sort | MFMA gemm1 (independent, overlapped)
    fsg1_kernel<<<NB + G1B, 256, 0, stream>>>(gcur, recsC, recs2, offs, ends,
                                              x, wfrag, support);

    // 4. h = relu(A @ support + b1)
    spmm1_kernel<<<(N_NODES + 3) / 4, 256, 0, stream>>>(offs, ends, recs2,
                                                        support, b1, h);

    // 5. s2 = h @ W2   (into support region)
    gemm2_kernel<<<(N_NODES + 127) / 128, 256, 0, stream>>>(h, W2, s2);

    // 6. out = A @ s2 + b2
    spmm2_kernel<<<(N_NODES + 3) / 4, 256, 0, stream>>>(offs, ends, recs2,
                                                        s2, b2, out);
}

// Round 18
// 136.395 us; speedup vs baseline: 1.3480x; 1.1098x over previous
//
#include <hip/hip_runtime.h>
#include <hip/hip_fp16.h>

#define N_NODES 100000
#define N_EDGES 1600000
#define NFEAT 128
#define NHID 64
#define NOUT 32

#define NPB 256                                   // nodes per bucket (dst >> 8)
#define NB ((N_NODES + NPB - 1) / NPB)            // 391 buckets
#define CAP 4608                                  // bucket window capacity
#define CCH 4096                                  // edges per scatter chunk
#define NCH ((N_EDGES + CCH - 1) / CCH)           // 391
#define G1B ((N_NODES / 16 + 3) / 4)              // 1563 gemm1 blocks

typedef _Float16 half8 __attribute__((ext_vector_type(8)));
typedef float floatx4 __attribute__((ext_vector_type(4)));

// wave-level inclusive scan (64 lanes), then 4-wave combine: 1 barrier total.
__device__ __forceinline__ int wave_incl_scan(int v, int lane) {
#pragma unroll
    for (int d = 1; d < 64; d <<= 1) {
        int t = __shfl_up(v, d, 64);
        if (lane >= d) v += t;
    }
    return v;
}
__device__ __forceinline__ int block_excl_scan_256(int tsum, int tid, int* w4) {
    const int lane = tid & 63, wid = tid >> 6;
    int incl = wave_incl_scan(tsum, lane);
    if (lane == 63) w4[wid] = incl;
    __syncthreads();
    int wbase = 0;
    if (wid > 0) wbase += w4[0];
    if (wid > 1) wbase += w4[1];
    if (wid > 2) wbase += w4[2];
    return wbase + incl - tsum;
}

// ---------------------------------------------------------------
// prep: blocks 0-15 W1->A-frags; 16-19 W2->A-frags; rest init gcur.
// ---------------------------------------------------------------
__global__ __launch_bounds__(64) void prep_kernel(const float* __restrict__ W1,
                                                  const float* __restrict__ W2,
                                                  __half* __restrict__ wfrag,
                                                  __half* __restrict__ w2frag,
                                                  int* __restrict__ gcur) {
    const int l = threadIdx.x;
    const int b = blockIdx.x;
    if (b < 16) {
        const int ks = b >> 2, ct = b & 3;
        const int kb = ks * 32 + (l >> 4) * 8;
        const int c  = ct * 16 + (l & 15);
        union { __half2 h2[4]; uint4 u; } pk;
#pragma unroll
        for (int j = 0; j < 4; ++j)
            pk.h2[j] = __floats2half2_rn(W1[(kb + 2 * j) * NHID + c],
                                         W1[(kb + 2 * j + 1) * NHID + c]);
        *(uint4*)&wfrag[((size_t)b * 64 + l) * 8] = pk.u;
    } else if (b < 20) {
        const int bb = b - 16;
        const int ks = bb >> 1, ct = bb & 1;
        const int kb = ks * 32 + (l >> 4) * 8;
        const int c  = ct * 16 + (l & 15);
        union { __half2 h2[4]; uint4 u; } pk;
#pragma unroll
        for (int j = 0; j < 4; ++j)
            pk.h2[j] = __floats2half2_rn(W2[(kb + 2 * j) * NOUT + c],
                                         W2[(kb + 2 * j + 1) * NOUT + c]);
        *(uint4*)&w2frag[((size_t)bb * 64 + l) * 8] = pk.u;
    } else {
        int i = (b - 20) * 64 + l;
        if (i < NB) gcur[i] = i * CAP;
    }
}

// ---------------------------------------------------------------
// fused: blocks [0,NCH) = lean coarse scatter (4096-edge chunks,
// direct line-local stores); rest = MFMA gemm1.  (R15-proven)
// record: x = src(17b) | dstLocal(8b)<<17 ; y = val f32 bits
// ---------------------------------------------------------------
__global__ __launch_bounds__(256) void g1cs_kernel(const float* __restrict__ x,
                                                   const __half* __restrict__ wfrag,
                                                   __half* __restrict__ support,
                                                   const float* __restrict__ vals,
                                                   const int* __restrict__ src,
                                                   const int* __restrict__ dst,
                                                   int* __restrict__ gcur,
                                                   uint2* __restrict__ recsC) {
    __shared__ int cnt[NB];
    __shared__ int pos[NB];
    const int tid = threadIdx.x;

    if (blockIdx.x < NCH) {
        const int cbase0 = blockIdx.x * CCH;
        for (int i = tid; i < NB; i += 256) cnt[i] = 0;
        int dstv[CCH / 256];
        __syncthreads();
#pragma unroll
        for (int k = 0; k < CCH / 256; ++k) {
            int e = cbase0 + k * 256 + tid;
            int d = (e < N_EDGES) ? dst[e] : -1;
            dstv[k] = d;
            if (d >= 0) atomicAdd(&cnt[d >> 8], 1);
        }
        __syncthreads();
        for (int b = tid; b < NB; b += 256) {
            int c = cnt[b];
            pos[b] = c ? atomicAdd(&gcur[b], c) : 0;
        }
        __syncthreads();
#pragma unroll
        for (int k = 0; k < CCH / 256; ++k) {
            int e = cbase0 + k * 256 + tid;
            int d = dstv[k];
            if (d >= 0) {
                int b = d >> 8;
                int slot = atomicAdd(&pos[b], 1);
                if (slot < (b + 1) * CAP)
                    recsC[slot] = make_uint2((unsigned)src[e] |
                                             ((unsigned)(d & (NPB - 1)) << 17),
                                             __float_as_uint(vals[e]));
            }
        }
    } else {
        // ------- MFMA gemm1: support = x @ W1 -------
        const int lane = tid & 63;
        const int tile = (blockIdx.x - NCH) * 4 + (tid >> 6);
        const int n0 = tile * 16;
        if (n0 >= N_NODES) return;

        half8 a[4][4];
#pragma unroll
        for (int ks = 0; ks < 4; ++ks)
#pragma unroll
            for (int ct = 0; ct < 4; ++ct)
                a[ks][ct] = *(const half8*)&wfrag[((size_t)(ks * 4 + ct) * 64 + lane) * 8];

        floatx4 acc[4];
#pragma unroll
        for (int ct = 0; ct < 4; ++ct) acc[ct] = (floatx4){0.f, 0.f, 0.f, 0.f};

        const int node = n0 + (lane & 15);
        const float* xrow = x + (size_t)node * NFEAT + (lane >> 4) * 8;

#pragma unroll
        for (int ks = 0; ks < 4; ++ks) {
            float4 f0 = *(const float4*)(xrow + ks * 32);
            float4 f1 = *(const float4*)(xrow + ks * 32 + 4);
            union { __half2 h2[4]; half8 v; } bv;
            bv.h2[0] = __floats2half2_rn(f0.x, f0.y);
            bv.h2[1] = __floats2half2_rn(f0.z, f0.w);
            bv.h2[2] = __floats2half2_rn(f1.x, f1.y);
            bv.h2[3] = __floats2half2_rn(f1.z, f1.w);
#pragma unroll
            for (int ct = 0; ct < 4; ++ct)
                acc[ct] = __builtin_amdgcn_mfma_f32_16x16x32_f16(a[ks][ct], bv.v, acc[ct], 0, 0, 0);
        }

        __half* srow = support + (size_t)node * NHID + (lane >> 4) * 4;
#pragma unroll
        for (int ct = 0; ct < 4; ++ct) {
            union { __half2 h2[2]; uint2 u; } pk;
            pk.h2[0] = __floats2half2_rn(acc[ct][0], acc[ct][1]);
            pk.h2[1] = __floats2half2_rn(acc[ct][2], acc[ct][3]);
            *(uint2*)&srow[ct * 16] = pk.u;
        }
    }
}

// ---------------------------------------------------------------
// fine sort: counting-sort each bucket window into exact node order
// ---------------------------------------------------------------
__global__ __launch_bounds__(256) void fine_sort_kernel(const int* __restrict__ gcur,
                                                        const uint2* __restrict__ recsC,
                                                        uint2* __restrict__ recs2,
                                                        int* __restrict__ offs,
                                                        int* __restrict__ ends) {
    __shared__ int cnt[NPB];
    __shared__ int cur[NPB];
    __shared__ int w4[4];
    const int tid = threadIdx.x;
    const int b = blockIdx.x;
    const int s = b * CAP;
    const int e = min(gcur[b], s + CAP);
    cnt[tid] = 0;
    __syncthreads();
    for (int i = s + tid; i < e; i += 256)
        atomicAdd(&cnt[(recsC[i].x >> 17) & (NPB - 1)], 1);
    __syncthreads();
    int v = cnt[tid];
    int excl = block_excl_scan_256(v, tid, w4);
    cur[tid] = excl;
    const int node = b * NPB + tid;
    if (node < N_NODES) {
        offs[node] = s + excl;
        ends[node] = s + excl + v;
    }
    __syncthreads();
    for (int i = s + tid; i < e; i += 256) {
        uint2 r = recsC[i];
        int dl = (r.x >> 17) & (NPB - 1);
        int p = atomicAdd(&cur[dl], 1);
        recs2[s + p] = make_uint2(r.x & 0x1FFFF, r.y);
    }
}

// ---------------------------------------------------------------
// SpMM1: h[d,:64] (fp16) = relu( sum val*support[src,:] + b1 )
// wave per node; 8 lanes/edge; packed __hfma2 inner loop (per-lane
// fp16 acc sums <=~7 bounded products; group-sum stays f32 in LDS).
// ---------------------------------------------------------------
__global__ __launch_bounds__(256) void spmm1_kernel(const int* __restrict__ offs,
                                                    const int* __restrict__ ends,
                                                    const uint2* __restrict__ recs,
                                                    const __half* __restrict__ dense,
                                                    const float* __restrict__ b1,
                                                    __half* __restrict__ h) {
    __shared__ float red[4][8][65];
    const int tid = threadIdx.x;
    const int lane = tid & 63;
    const int wid = tid >> 6;
    const int d = blockIdx.x * 4 + wid;
    if (d >= N_NODES) return;
    const int g = lane >> 3, q = lane & 7;
    __half2 hacc[4];
#pragma unroll
    for (int j = 0; j < 4; ++j) hacc[j] = __half2half2(__float2half(0.f));

    const int start = offs[d], end = ends[d];
    for (int e = start + g; e < end; e += 8) {
        uint2 r = recs[e];
        __half2 hv2 = __half2half2(__float2half(__uint_as_float(r.y)));
        union { uint4 u; __half2 h2[4]; } rw;
        rw.u = *(const uint4*)((const char*)dense + ((size_t)r.x << 7) + (q << 4));
#pragma unroll
        for (int j = 0; j < 4; ++j)
            hacc[j] = __hfma2(rw.h2[j], hv2, hacc[j]);
    }
#pragma unroll
    for (int j = 0; j < 4; ++j) {
        float2 f = __half22float2(hacc[j]);
        red[wid][g][q * 8 + 2 * j]     = f.x;
        red[wid][g][q * 8 + 2 * j + 1] = f.y;
    }
    __builtin_amdgcn_wave_barrier();
    float s = 0.f;
#pragma unroll
    for (int gg = 0; gg < 8; ++gg) s += red[wid][gg][lane];
    float hv = fmaxf(s + b1[lane], 0.f);
    h[(size_t)d * NHID + lane] = __float2half(hv);
}

// ---------------------------------------------------------------
// GEMM2 (MFMA): s2[N,32] (fp16) = h[N,64] (fp16) @ W2[64,32]
// Same fragment scheme as gemm1; h rows load directly as B-frags.
// ---------------------------------------------------------------
__global__ __launch_bounds__(256) void gemm2_kernel(const __half* __restrict__ h,
                                                    const __half* __restrict__ w2frag,
                                                    __half* __restrict__ s2) {
    const int lane = threadIdx.x & 63;
    const int tile = blockIdx.x * 4 + (threadIdx.x >> 6);
    const int n0 = tile * 16;
    if (n0 >= N_NODES) return;

    half8 a[2][2];
#pragma unroll
    for (int ks = 0; ks < 2; ++ks)
#pragma unroll
        for (int ct = 0; ct < 2; ++ct)
            a[ks][ct] = *(const half8*)&w2frag[((size_t)(ks * 2 + ct) * 64 + lane) * 8];

    floatx4 acc[2];
#pragma unroll
    for (int ct = 0; ct < 2; ++ct) acc[ct] = (floatx4){0.f, 0.f, 0.f, 0.f};

    const int node = n0 + (lane & 15);
    const __half* hrow = h + (size_t)node * NHID + (lane >> 4) * 8;

#pragma unroll
    for (int ks = 0; ks < 2; ++ks) {
        half8 bv = *(const half8*)(hrow + ks * 32);
#pragma unroll
        for (int ct = 0; ct < 2; ++ct)
            acc[ct] = __builtin_amdgcn_mfma_f32_16x16x32_f16(a[ks][ct], bv, acc[ct], 0, 0, 0);
    }

    __half* srow = s2 + (size_t)node * NOUT + (lane >> 4) * 4;
#pragma unroll
    for (int ct = 0; ct < 2; ++ct) {
        union { __half2 h2[2]; uint2 u; } pk;
        pk.h2[0] = __floats2half2_rn(acc[ct][0], acc[ct][1]);
        pk.h2[1] = __floats2half2_rn(acc[ct][2], acc[ct][3]);
        *(uint2*)&srow[ct * 16] = pk.u;
    }
}

// ---------------------------------------------------------------
// SpMM2: out[d,:32] (fp32) = sum val*s2[src,:] + b2
// wave per node; 4 lanes/edge; packed __hfma2 inner loop.
// ---------------------------------------------------------------
__global__ __launch_bounds__(256) void spmm2_kernel(const int* __restrict__ offs,
                                                    const int* __restrict__ ends,
                                                    const uint2* __restrict__ recs,
                                                    const __half* __restrict__ dense,
                                                    const float* __restrict__ b2,
                                                    float* __restrict__ out) {
    __shared__ float red[4][16][33];
    const int tid = threadIdx.x;
    const int lane = tid & 63;
    const int wid = tid >> 6;
    const int d = blockIdx.x * 4 + wid;
    if (d >= N_NODES) return;
    const int g = lane >> 2, q = lane & 3;
    __half2 hacc[4];
#pragma unroll
    for (int j = 0; j < 4; ++j) hacc[j] = __half2half2(__float2half(0.f));

    const int start = offs[d], end = ends[d];
    for (int e = start + g; e < end; e += 16) {
        uint2 r = recs[e];
        __half2 hv2 = __half2half2(__float2half(__uint_as_float(r.y)));
        union { uint4 u; __half2 h2[4]; } rw;
        rw.u = *(const uint4*)((const char*)dense + ((size_t)r.x << 6) + (q << 4));
#pragma unroll
        for (int j = 0; j < 4; ++j)
            hacc[j] = __hfma2(rw.h2[j], hv2, hacc[j]);
    }
#pragma unroll
    for (int j = 0; j < 4; ++j) {
        float2 f = __half22float2(hacc[j]);
        red[wid][g][q * 8 + 2 * j]     = f.x;
        red[wid][g][q * 8 + 2 * j + 1] = f.y;
    }
    __builtin_amdgcn_wave_barrier();
    const int f = lane & 31, hi = lane >> 5;
    float s = 0.f;
#pragma unroll
    for (int t = 0; t < 8; ++t) s += red[wid][hi * 8 + t][f];
    s += __shfl_xor(s, 32, 64);
    if (hi == 0) out[(size_t)d * NOUT + f] = s + b2[f];
}

extern "C" void kernel_launch(void* const* d_in, const int* in_sizes, int n_in,
                              void* d_out, int out_size, void* d_ws, size_t ws_size,
                              hipStream_t stream) {
    const float* x        = (const float*)d_in[0];
    const float* adj_vals = (const float*)d_in[1];
    const float* W1       = (const float*)d_in[2];
    const float* b1       = (const float*)d_in[3];
    const float* W2       = (const float*)d_in[4];
    const float* b2       = (const float*)d_in[5];
    const int*   esrc     = (const int*)d_in[6];
    const int*   edst     = (const int*)d_in[7];
    float*       out      = (float*)d_out;

    // ws layout (~55.3 MB, all regions rewritten every call):
    //   support[12.8MB] (s2 aliases; support dead after spmm1) | h[12.8MB]
    //   recsC[14.41MB] | recs2[14.41MB] | offs | ends | gcur | wfrag | w2frag
    char* W = (char*)d_ws;
    __half* support = (__half*)W;
    __half* h       = (__half*)(W + 12800000);
    uint2*  recsC   = (uint2*)(W + 25600000);
    uint2*  recs2   = (uint2*)(W + 25600000 + (size_t)NB * CAP * 8);
    int*    IW      = (int*)(W + 25600000 + 2 * (size_t)NB * CAP * 8);
    int*    offs    = IW;                      // N
    int*    ends    = IW + 100032;             // N
    int*    gcur    = IW + 200064;             // NB
    __half* wfrag   = (__half*)(IW + 200064 + 512);   // 8192 halves
    __half* w2frag  = wfrag + 8192;                   // 2048 halves
    __half* s2      = support;

    // 1. prep: W1/W2 fragment swizzle + gcur init
    prep_kernel<<<20 + (NB + 63) / 64, 64, 0, stream>>>(W1, W2, wfrag, w2frag, gcur);

    // 2. fused: lean coarse scatter | MFMA gemm1 (R15-proven)
    g1cs_kernel<<<NCH + G1B, 256, 0, stream>>>(x, wfrag, support,
                                               adj_vals, esrc, edst, gcur, recsC);

    // 3. fine sort -> recs2, offs/ends
    fine_sort_kernel<<<NB, 256, 0, stream>>>(gcur, recsC, recs2, offs, ends);

    // 4. h = relu(A @ support + b1)
    spmm1_kernel<<<(N_NODES + 3) / 4, 256, 0, stream>>>(offs, ends, recs2,
                                                        support, b1, h);

    // 5. s2 = h @ W2  (MFMA, into support region)
    gemm2_kernel<<<(N_NODES / 16 + 3) / 4, 256, 0, stream>>>(h, w2frag, s2);

    // 6. out = A @ s2 + b2
    spmm2_kernel<<<(N_NODES + 3) / 4, 256, 0, stream>>>(offs, ends, recs2,
                                                        s2, b2, out);
}

// Round 19
// 134.315 us; speedup vs baseline: 1.3689x; 1.0155x over previous
//
#include <hip/hip_runtime.h>
#include <hip/hip_fp16.h>

#define N_NODES 100000
#define N_EDGES 1600000
#define NFEAT 128
#define NHID 64
#define NOUT 32

#define NPB 256                                   // nodes per bucket (dst >> 8)
#define NB ((N_NODES + NPB - 1) / NPB)            // 391 buckets
#define CAP 4608                                  // bucket window capacity
#define CCH 4096                                  // edges per scatter chunk
#define NCH ((N_EDGES + CCH - 1) / CCH)           // 391
#define G1B ((N_NODES / 16 + 7) / 8)              // 782 gemm1 blocks (8 tiles each)

typedef _Float16 half8 __attribute__((ext_vector_type(8)));
typedef float floatx4 __attribute__((ext_vector_type(4)));

// wave-level inclusive scan (64 lanes)
__device__ __forceinline__ int wave_incl_scan(int v, int lane) {
#pragma unroll
    for (int d = 1; d < 64; d <<= 1) {
        int t = __shfl_up(v, d, 64);
        if (lane >= d) v += t;
    }
    return v;
}
// exclusive prefix over a 512-thread block (per-thread value tsum).
__device__ __forceinline__ int block_excl_scan_512(int tsum, int tid, int* w8) {
    const int lane = tid & 63, wid = tid >> 6;
    int incl = wave_incl_scan(tsum, lane);
    if (lane == 63) w8[wid] = incl;
    __syncthreads();
    int wbase = 0;
#pragma unroll
    for (int i = 0; i < 7; ++i)
        if (wid > i) wbase += w8[i];
    return wbase + incl - tsum;
}

// ---------------------------------------------------------------
// prep: blocks 0-15 W1->A-frags; 16-19 W2->A-frags; rest init gcur.
// ---------------------------------------------------------------
__global__ __launch_bounds__(64) void prep_kernel(const float* __restrict__ W1,
                                                  const float* __restrict__ W2,
                                                  __half* __restrict__ wfrag,
                                                  __half* __restrict__ w2frag,
                                                  int* __restrict__ gcur) {
    const int l = threadIdx.x;
    const int b = blockIdx.x;
    if (b < 16) {
        const int ks = b >> 2, ct = b & 3;
        const int kb = ks * 32 + (l >> 4) * 8;
        const int c  = ct * 16 + (l & 15);
        union { __half2 h2[4]; uint4 u; } pk;
#pragma unroll
        for (int j = 0; j < 4; ++j)
            pk.h2[j] = __floats2half2_rn(W1[(kb + 2 * j) * NHID + c],
                                         W1[(kb + 2 * j + 1) * NHID + c]);
        *(uint4*)&wfrag[((size_t)b * 64 + l) * 8] = pk.u;
    } else if (b < 20) {
        const int bb = b - 16;
        const int ks = bb >> 1, ct = bb & 1;
        const int kb = ks * 32 + (l >> 4) * 8;
        const int c  = ct * 16 + (l & 15);
        union { __half2 h2[4]; uint4 u; } pk;
#pragma unroll
        for (int j = 0; j < 4; ++j)
            pk.h2[j] = __floats2half2_rn(W2[(kb + 2 * j) * NOUT + c],
                                         W2[(kb + 2 * j + 1) * NOUT + c]);
        *(uint4*)&w2frag[((size_t)bb * 64 + l) * 8] = pk.u;
    } else {
        int i = (b - 20) * 64 + l;
        if (i < NB) gcur[i] = i * CAP;
    }
}

// ---------------------------------------------------------------
// fused (512 threads): blocks [0,NCH) = lean coarse scatter
// (4096-edge chunks, 8 edges/thread, 8 waves/block for tail
// latency-hiding); blocks [NCH,..) = MFMA gemm1 (8 tiles/block).
// record: x = src(17b) | dstLocal(8b)<<17 ; y = val f32 bits
// ---------------------------------------------------------------
__global__ __launch_bounds__(512) void g1cs_kernel(const float* __restrict__ x,
                                                   const __half* __restrict__ wfrag,
                                                   __half* __restrict__ support,
                                                   const float* __restrict__ vals,
                                                   const int* __restrict__ src,
                                                   const int* __restrict__ dst,
                                                   int* __restrict__ gcur,
                                                   uint2* __restrict__ recsC) {
    __shared__ int cnt[NB];
    __shared__ int pos[NB];
    const int tid = threadIdx.x;

    if (blockIdx.x < NCH) {
        const int cbase0 = blockIdx.x * CCH;
        for (int i = tid; i < NB; i += 512) cnt[i] = 0;
        int dstv[CCH / 512];
        __syncthreads();
#pragma unroll
        for (int k = 0; k < CCH / 512; ++k) {
            int e = cbase0 + k * 512 + tid;
            int d = (e < N_EDGES) ? dst[e] : -1;
            dstv[k] = d;
            if (d >= 0) atomicAdd(&cnt[d >> 8], 1);
        }
        __syncthreads();
        for (int b = tid; b < NB; b += 512) {
            int c = cnt[b];
            pos[b] = c ? atomicAdd(&gcur[b], c) : 0;
        }
        __syncthreads();
#pragma unroll
        for (int k = 0; k < CCH / 512; ++k) {
            int e = cbase0 + k * 512 + tid;
            int d = dstv[k];
            if (d >= 0) {
                int b = d >> 8;
                int slot = atomicAdd(&pos[b], 1);
                if (slot < (b + 1) * CAP)
                    recsC[slot] = make_uint2((unsigned)src[e] |
                                             ((unsigned)(d & (NPB - 1)) << 17),
                                             __float_as_uint(vals[e]));
            }
        }
    } else {
        // ------- MFMA gemm1: support = x @ W1 (8 tiles per block) -------
        const int lane = tid & 63;
        const int tile = (blockIdx.x - NCH) * 8 + (tid >> 6);
        const int n0 = tile * 16;
        if (n0 >= N_NODES) return;

        half8 a[4][4];
#pragma unroll
        for (int ks = 0; ks < 4; ++ks)
#pragma unroll
            for (int ct = 0; ct < 4; ++ct)
                a[ks][ct] = *(const half8*)&wfrag[((size_t)(ks * 4 + ct) * 64 + lane) * 8];

        floatx4 acc[4];
#pragma unroll
        for (int ct = 0; ct < 4; ++ct) acc[ct] = (floatx4){0.f, 0.f, 0.f, 0.f};

        const int node = n0 + (lane & 15);
        const float* xrow = x + (size_t)node * NFEAT + (lane >> 4) * 8;

#pragma unroll
        for (int ks = 0; ks < 4; ++ks) {
            float4 f0 = *(const float4*)(xrow + ks * 32);
            float4 f1 = *(const float4*)(xrow + ks * 32 + 4);
            union { __half2 h2[4]; half8 v; } bv;
            bv.h2[0] = __floats2half2_rn(f0.x, f0.y);
            bv.h2[1] = __floats2half2_rn(f0.z, f0.w);
            bv.h2[2] = __floats2half2_rn(f1.x, f1.y);
            bv.h2[3] = __floats2half2_rn(f1.z, f1.w);
#pragma unroll
            for (int ct = 0; ct < 4; ++ct)
                acc[ct] = __builtin_amdgcn_mfma_f32_16x16x32_f16(a[ks][ct], bv.v, acc[ct], 0, 0, 0);
        }

        __half* srow = support + (size_t)node * NHID + (lane >> 4) * 4;
#pragma unroll
        for (int ct = 0; ct < 4; ++ct) {
            union { __half2 h2[2]; uint2 u; } pk;
            pk.h2[0] = __floats2half2_rn(acc[ct][0], acc[ct][1]);
            pk.h2[1] = __floats2half2_rn(acc[ct][2], acc[ct][3]);
            *(uint2*)&srow[ct * 16] = pk.u;
        }
    }
}

// ---------------------------------------------------------------
// fine sort (512 threads): counting-sort each bucket window into
// exact node order; 8 waves/block for tail latency-hiding.
// ---------------------------------------------------------------
__global__ __launch_bounds__(512) void fine_sort_kernel(const int* __restrict__ gcur,
                                                        const uint2* __restrict__ recsC,
                                                        uint2* __restrict__ recs2,
                                                        int* __restrict__ offs,
                                                        int* __restrict__ ends) {
    __shared__ int cnt[NPB];
    __shared__ int cur[NPB];
    __shared__ int w8[8];
    const int tid = threadIdx.x;
    const int b = blockIdx.x;
    const int s = b * CAP;
    const int e = min(gcur[b], s + CAP);
    if (tid < NPB) cnt[tid] = 0;
    __syncthreads();
    for (int i = s + tid; i < e; i += 512)
        atomicAdd(&cnt[(recsC[i].x >> 17) & (NPB - 1)], 1);
    __syncthreads();
    int v = (tid < NPB) ? cnt[tid] : 0;
    int excl = block_excl_scan_512(v, tid, w8);
    if (tid < NPB) {
        cur[tid] = excl;
        const int node = b * NPB + tid;
        if (node < N_NODES) {
            offs[node] = s + excl;
            ends[node] = s + excl + v;
        }
    }
    __syncthreads();
    for (int i = s + tid; i < e; i += 512) {
        uint2 r = recsC[i];
        int dl = (r.x >> 17) & (NPB - 1);
        int p = atomicAdd(&cur[dl], 1);
        recs2[s + p] = make_uint2(r.x & 0x1FFFF, r.y);
    }
}

// ---------------------------------------------------------------
// SpMM1: h[d,:64] (fp16) = relu( sum val*support[src,:] + b1 )
// wave per node; 8 lanes/edge; packed __hfma2 inner loop.
// ---------------------------------------------------------------
__global__ __launch_bounds__(256) void spmm1_kernel(const int* __restrict__ offs,
                                                    const int* __restrict__ ends,
                                                    const uint2* __restrict__ recs,
                                                    const __half* __restrict__ dense,
                                                    const float* __restrict__ b1,
                                                    __half* __restrict__ h) {
    __shared__ float red[4][8][65];
    const int tid = threadIdx.x;
    const int lane = tid & 63;
    const int wid = tid >> 6;
    const int d = blockIdx.x * 4 + wid;
    if (d >= N_NODES) return;
    const int g = lane >> 3, q = lane & 7;
    __half2 hacc[4];
#pragma unroll
    for (int j = 0; j < 4; ++j) hacc[j] = __half2half2(__float2half(0.f));

    const int start = offs[d], end = ends[d];
    for (int e = start + g; e < end; e += 8) {
        uint2 r = recs[e];
        __half2 hv2 = __half2half2(__float2half(__uint_as_float(r.y)));
        union { uint4 u; __half2 h2[4]; } rw;
        rw.u = *(const uint4*)((const char*)dense + ((size_t)r.x << 7) + (q << 4));
#pragma unroll
        for (int j = 0; j < 4; ++j)
            hacc[j] = __hfma2(rw.h2[j], hv2, hacc[j]);
    }
#pragma unroll
    for (int j = 0; j < 4; ++j) {
        float2 f = __half22float2(hacc[j]);
        red[wid][g][q * 8 + 2 * j]     = f.x;
        red[wid][g][q * 8 + 2 * j + 1] = f.y;
    }
    __builtin_amdgcn_wave_barrier();
    float s = 0.f;
#pragma unroll
    for (int gg = 0; gg < 8; ++gg) s += red[wid][gg][lane];
    float hv = fmaxf(s + b1[lane], 0.f);
    h[(size_t)d * NHID + lane] = __float2half(hv);
}

// ---------------------------------------------------------------
// GEMM2 (MFMA): s2[N,32] (fp16) = h[N,64] (fp16) @ W2[64,32]
// ---------------------------------------------------------------
__global__ __launch_bounds__(256) void gemm2_kernel(const __half* __restrict__ h,
                                                    const __half* __restrict__ w2frag,
                                                    __half* __restrict__ s2) {
    const int lane = threadIdx.x & 63;
    const int tile = blockIdx.x * 4 + (threadIdx.x >> 6);
    const int n0 = tile * 16;
    if (n0 >= N_NODES) return;

    half8 a[2][2];
#pragma unroll
    for (int ks = 0; ks < 2; ++ks)
#pragma unroll
        for (int ct = 0; ct < 2; ++ct)
            a[ks][ct] = *(const half8*)&w2frag[((size_t)(ks * 2 + ct) * 64 + lane) * 8];

    floatx4 acc[2];
#pragma unroll
    for (int ct = 0; ct < 2; ++ct) acc[ct] = (floatx4){0.f, 0.f, 0.f, 0.f};

    const int node = n0 + (lane & 15);
    const __half* hrow = h + (size_t)node * NHID + (lane >> 4) * 8;

#pragma unroll
    for (int ks = 0; ks < 2; ++ks) {
        half8 bv = *(const half8*)(hrow + ks * 32);
#pragma unroll
        for (int ct = 0; ct < 2; ++ct)
            acc[ct] = __builtin_amdgcn_mfma_f32_16x16x32_f16(a[ks][ct], bv, acc[ct], 0, 0, 0);
    }

    __half* srow = s2 + (size_t)node * NOUT + (lane >> 4) * 4;
#pragma unroll
    for (int ct = 0; ct < 2; ++ct) {
        union { __half2 h2[2]; uint2 u; } pk;
        pk.h2[0] = __floats2half2_rn(acc[ct][0], acc[ct][1]);
        pk.h2[1] = __floats2half2_rn(acc[ct][2], acc[ct][3]);
        *(uint2*)&srow[ct * 16] = pk.u;
    }
}

// ---------------------------------------------------------------
// SpMM2: out[d,:32] (fp32) = sum val*s2[src,:] + b2
// wave per node; 4 lanes/edge; packed __hfma2 inner loop.
// ---------------------------------------------------------------
__global__ __launch_bounds__(256) void spmm2_kernel(const int* __restrict__ offs,
                                                    const int* __restrict__ ends,
                                                    const uint2* __restrict__ recs,
                                                    const __half* __restrict__ dense,
                                                    const float* __restrict__ b2,
                                                    float* __restrict__ out) {
    __shared__ float red[4][16][33];
    const int tid = threadIdx.x;
    const int lane = tid & 63;
    const int wid = tid >> 6;
    const int d = blockIdx.x * 4 + wid;
    if (d >= N_NODES) return;
    const int g = lane >> 2, q = lane & 3;
    __half2 hacc[4];
#pragma unroll
    for (int j = 0; j < 4; ++j) hacc[j] = __half2half2(__float2half(0.f));

    const int start = offs[d], end = ends[d];
    for (int e = start + g; e < end; e += 16) {
        uint2 r = recs[e];
        __half2 hv2 = __half2half2(__float2half(__uint_as_float(r.y)));
        union { uint4 u; __half2 h2[4]; } rw;
        rw.u = *(const uint4*)((const char*)dense + ((size_t)r.x << 6) + (q << 4));
#pragma unroll
        for (int j = 0; j < 4; ++j)
            hacc[j] = __hfma2(rw.h2[j], hv2, hacc[j]);
    }
#pragma unroll
    for (int j = 0; j < 4; ++j) {
        float2 f = __half22float2(hacc[j]);
        red[wid][g][q * 8 + 2 * j]     = f.x;
        red[wid][g][q * 8 + 2 * j + 1] = f.y;
    }
    __builtin_amdgcn_wave_barrier();
    const int f = lane & 31, hi = lane >> 5;
    float s = 0.f;
#pragma unroll
    for (int t = 0; t < 8; ++t) s += red[wid][hi * 8 + t][f];
    s += __shfl_xor(s, 32, 64);
    if (hi == 0) out[(size_t)d * NOUT + f] = s + b2[f];
}

extern "C" void kernel_launch(void* const* d_in, const int* in_sizes, int n_in,
                              void* d_out, int out_size, void* d_ws, size_t ws_size,
                              hipStream_t stream) {
    const float* x        = (const float*)d_in[0];
    const float* adj_vals = (const float*)d_in[1];
    const float* W1       = (const float*)d_in[2];
    const float* b1       = (const float*)d_in[3];
    const float* W2       = (const float*)d_in[4];
    const float* b2       = (const float*)d_in[5];
    const int*   esrc     = (const int*)d_in[6];
    const int*   edst     = (const int*)d_in[7];
    float*       out      = (float*)d_out;

    // ws layout (~55.3 MB, all regions rewritten every call):
    //   support[12.8MB] (s2 aliases; support dead after spmm1) | h[12.8MB]
    //   recsC[14.41MB] | recs2[14.41MB] | offs | ends | gcur | wfrag | w2frag
    char* W = (char*)d_ws;
    __half* support = (__half*)W;
    __half* h       = (__half*)(W + 12800000);
    uint2*  recsC   = (uint2*)(W + 25600000);
    uint2*  recs2   = (uint2*)(W + 25600000 + (size_t)NB * CAP * 8);
    int*    IW      = (int*)(W + 25600000 + 2 * (size_t)NB * CAP * 8);
    int*    offs    = IW;                      // N
    int*    ends    = IW + 100032;             // N
    int*    gcur    = IW + 200064;             // NB
    __half* wfrag   = (__half*)(IW + 200064 + 512);   // 8192 halves
    __half* w2frag  = wfrag + 8192;                   // 2048 halves
    __half* s2      = support;

    // 1. prep: W1/W2 fragment swizzle + gcur init
    prep_kernel<<<20 + (NB + 63) / 64, 64, 0, stream>>>(W1, W2, wfrag, w2frag, gcur);

    // 2. fused: lean coarse scatter | MFMA gemm1 (512-thread blocks)
    g1cs_kernel<<<NCH + G1B, 512, 0, stream>>>(x, wfrag, support,
                                               adj_vals, esrc, edst, gcur, recsC);

    // 3. fine sort -> recs2, offs/ends (512-thread blocks)
    fine_sort_kernel<<<NB, 512, 0, stream>>>(gcur, recsC, recs2, offs, ends);

    // 4. h = relu(A @ support + b1)
    spmm1_kernel<<<(N_NODES + 3) / 4, 256, 0, stream>>>(offs, ends, recs2,
                                                        support, b1, h);

    // 5. s2 = h @ W2  (MFMA, into support region)
    gemm2_kernel<<<(N_NODES / 16 + 3) / 4, 256, 0, stream>>>(h, w2frag, s2);

    // 6. out = A @ s2 + b2
    spmm2_kernel<<<(N_NODES + 3) / 4, 256, 0, stream>>>(offs, ends, recs2,
                                                        s2, b2, out);
}